// Round 3
// baseline (107.328 us; speedup 1.0000x reference)
//
#include <hip/hip_runtime.h>

typedef float f2 __attribute__((ext_vector_type(2)));

#define HH 512
#define WW 512
#define NB 32
#define RB 4                        // output rows per thread (vertical blocking)
#define HG_N (HH / RB)              // 128 row-groups
#define NTHREAD (NB * HG_N * WW)    // 2,097,152
#define EPS 1e-5f

__device__ __forceinline__ float4 ldx4(const float* __restrict__ x, int b, int h, int w) {
    return *reinterpret_cast<const float4*>(x + ((((size_t)b * HH + h) * WW + w) << 2));
}

// load the K-wide horizontal float4 window centered at w for input row hh
template <int K>
__device__ __forceinline__ void load_rowv(const float* __restrict__ x, int b, int hh,
                                          int w, float4 rb[K]) {
    constexpr int P = K / 2;
    if ((unsigned)hh < (unsigned)HH) {       // wave-uniform branch
#pragma unroll
        for (int j = 0; j < K; ++j) {
            int ww = w - P + j;
            rb[j] = ((unsigned)ww < (unsigned)WW) ? ldx4(x, b, hh, ww)
                                                  : float4{0.f, 0.f, 0.f, 0.f};
        }
    } else {
#pragma unroll
        for (int j = 0; j < K; ++j) rb[j] = float4{0.f, 0.f, 0.f, 0.f};
    }
}

// Vertical-column conv: 4 output rows at fixed w. Streams input rows with a
// 2-deep register double buffer (all indices compile-time after full unroll).
// full: weights HWIO [K][K][4][4]; dw: [K][K][1][4]. acc split ch{0,1}/{2,3}.
template <int K, bool DW>
__device__ __forceinline__ void conv_vert(const float* __restrict__ x,
                                          const float* __restrict__ wgt,
                                          int b, int h0, int w,
                                          f2 accl[RB], f2 acch[RB]) {
    constexpr int P = K / 2;
    constexpr int NR = RB + 2 * P;  // input rows touched
    float4 rb[2][K];
    load_rowv<K>(x, b, h0 - P, w, rb[0]);
#pragma unroll
    for (int i = 0; i < NR; ++i) {
        int ir = i - P;                                  // input row offset vs h0
        if (i + 1 < NR) load_rowv<K>(x, b, h0 + ir + 1, w, rb[(i + 1) & 1]);
        const float4* cur = rb[i & 1];
#pragma unroll
        for (int r = 0; r < RB; ++r) {
            int ki = ir - r + P;                         // compile-time per (i,r)
            if (ki < 0 || ki >= K) continue;
#pragma unroll
            for (int kj = 0; kj < K; ++kj) {
                float4 p = cur[kj];
                if (DW) {
                    const float* wp = wgt + (ki * K + kj) * 4;
                    accl[r] += f2{p.x, p.y} * f2{wp[0], wp[1]};
                    acch[r] += f2{p.z, p.w} * f2{wp[2], wp[3]};
                } else {
                    const float* wp = wgt + (ki * K + kj) * 16;  // [in][out] 4x4
                    accl[r] += p.x * f2{wp[0],  wp[1]}  + p.y * f2{wp[4],  wp[5]}
                             + p.z * f2{wp[8],  wp[9]}  + p.w * f2{wp[12], wp[13]};
                    acch[r] += p.x * f2{wp[2],  wp[3]}  + p.y * f2{wp[6],  wp[7]}
                             + p.z * f2{wp[10], wp[11]} + p.w * f2{wp[14], wp[15]};
                }
            }
        }
    }
}

__global__ __launch_bounds__(256) void mixop_kernel(
    const float* __restrict__ x,
    const float* __restrict__ logits, const float* __restrict__ g,
    const float* __restrict__ w0, const float* __restrict__ w1,
    const float* __restrict__ w2, const float* __restrict__ w3,
    const float* __restrict__ w4,
    const float* __restrict__ gamma, const float* __restrict__ beta,
    const float* __restrict__ mean, const float* __restrict__ var,
    float* __restrict__ out) {
    int tid = blockIdx.x * blockDim.x + threadIdx.x;

    // wave-uniform routing: argmax(logits + g), first-max wins
    int idx = 0;
    float best = logits[0] + g[0];
#pragma unroll
    for (int i = 1; i < 5; ++i) {
        float v = logits[i] + g[i];
        if (v > best) { best = v; idx = i; }
    }

    int w  = tid & (WW - 1);            // lanes carry consecutive w -> coalesced
    int hg = (tid >> 9) & (HG_N - 1);   // wave-uniform
    int b  = tid >> 16;
    int h0 = hg * RB;

    f2 accl[RB] = {f2{0.f,0.f}, f2{0.f,0.f}, f2{0.f,0.f}, f2{0.f,0.f}};
    f2 acch[RB] = {f2{0.f,0.f}, f2{0.f,0.f}, f2{0.f,0.f}, f2{0.f,0.f}};

    switch (idx) {
        case 0: conv_vert<1, false>(x, w0, b, h0, w, accl, acch); break;
        case 1: conv_vert<3, false>(x, w1, b, h0, w, accl, acch); break;
        case 2: conv_vert<3, true >(x, w2, b, h0, w, accl, acch); break;
        case 3: conv_vert<5, false>(x, w3, b, h0, w, accl, acch); break;
        case 4: conv_vert<5, true >(x, w4, b, h0, w, accl, acch); break;
    }

    // inference BN + ReLU; final routing scale == 1.0 exactly (onehot+soft-soft)
    const float* ga = gamma + idx * 4;
    const float* be = beta + idx * 4;
    const float* mu = mean + idx * 4;
    const float* vr = var + idx * 4;
    f2 ivl = {ga[0] * rsqrtf(vr[0] + EPS), ga[1] * rsqrtf(vr[1] + EPS)};
    f2 ivh = {ga[2] * rsqrtf(vr[2] + EPS), ga[3] * rsqrtf(vr[3] + EPS)};
    f2 shl = f2{be[0], be[1]} - f2{mu[0], mu[1]} * ivl;
    f2 shh = f2{be[2], be[3]} - f2{mu[2], mu[3]} * ivh;

#pragma unroll
    for (int r = 0; r < RB; ++r) {
        f2 ol = accl[r] * ivl + shl;
        f2 oh = acch[r] * ivh + shh;
        float4 o;
        o.x = ol.x > 0.f ? ol.x : 0.f;
        o.y = ol.y > 0.f ? ol.y : 0.f;
        o.z = oh.x > 0.f ? oh.x : 0.f;
        o.w = oh.y > 0.f ? oh.y : 0.f;
        *reinterpret_cast<float4*>(out + ((((size_t)b * HH + h0 + r) * WW + w) << 2)) = o;
    }
}

extern "C" void kernel_launch(void* const* d_in, const int* in_sizes, int n_in,
                              void* d_out, int out_size, void* d_ws, size_t ws_size,
                              hipStream_t stream) {
    const float* x      = (const float*)d_in[0];
    const float* logits = (const float*)d_in[1];
    const float* g      = (const float*)d_in[2];
    const float* w0     = (const float*)d_in[3];
    const float* w1     = (const float*)d_in[4];
    const float* w2     = (const float*)d_in[5];
    const float* w3     = (const float*)d_in[6];
    const float* w4     = (const float*)d_in[7];
    const float* gamma  = (const float*)d_in[8];
    const float* beta   = (const float*)d_in[9];
    const float* mean   = (const float*)d_in[10];
    const float* var    = (const float*)d_in[11];
    float* out = (float*)d_out;

    const int threads = 256;
    const int blocks = NTHREAD / threads;   // exact multiple
    mixop_kernel<<<blocks, threads, 0, stream>>>(
        x, logits, g, w0, w1, w2, w3, w4, gamma, beta, mean, var, out);
}

// Round 4
// 75.006 us; speedup vs baseline: 1.4309x; 1.4309x over previous
//
#include <hip/hip_runtime.h>

typedef float f2 __attribute__((ext_vector_type(2)));

#define HH 512
#define WW 512
#define NB 32
#define TW 64                    // output tile width (px)
#define TH 16                    // output tile height
#define RB 4                     // rows per thread (ty 0..3 -> rows 4ty..4ty+3)
#define TIW (TW + 4)             // 68 (halo P<=2 each side)
#define TIH (TH + 4)             // 20
#define NTILE (TIW * TIH)        // 1360
#define EPS 1e-5f

__device__ __forceinline__ float4 ldx4(const float* __restrict__ x, int b, int h, int w) {
    return *reinterpret_cast<const float4*>(x + ((((size_t)b * HH + h) * WW + w) << 2));
}

// compute RB vertical output px from the staged tile; weights HWIO
template <int K, bool DW>
__device__ __forceinline__ void conv_tile(const float4* __restrict__ tile,  // [TIH][TIW]
                                          const float* __restrict__ wgt,
                                          int tx, int ty,
                                          f2 accl[RB], f2 acch[RB]) {
    constexpr int P = K / 2;
#pragma unroll
    for (int i = 0; i < RB + 2 * P; ++i) {
        const float4* trow = tile + (ty * RB + (2 - P) + i) * TIW + tx + (2 - P);
        float4 win[K];
#pragma unroll
        for (int kj = 0; kj < K; ++kj) win[kj] = trow[kj];
#pragma unroll
        for (int r = 0; r < RB; ++r) {
            int ki = i - r;                       // compile-time per (i,r)
            if (ki < 0 || ki >= K) continue;
#pragma unroll
            for (int kj = 0; kj < K; ++kj) {
                float4 p = win[kj];
                if (DW) {
                    const float* wp = wgt + (ki * K + kj) * 4;   // [c]
                    accl[r] += f2{p.x, p.y} * f2{wp[0], wp[1]};
                    acch[r] += f2{p.z, p.w} * f2{wp[2], wp[3]};
                } else {
                    const float* wp = wgt + (ki * K + kj) * 16;  // [in][out] 4x4
                    accl[r] += p.x * f2{wp[0],  wp[1]}  + p.y * f2{wp[4],  wp[5]}
                             + p.z * f2{wp[8],  wp[9]}  + p.w * f2{wp[12], wp[13]};
                    acch[r] += p.x * f2{wp[2],  wp[3]}  + p.y * f2{wp[6],  wp[7]}
                             + p.z * f2{wp[10], wp[11]} + p.w * f2{wp[14], wp[15]};
                }
            }
        }
    }
}

__global__ __launch_bounds__(256) void mixop_kernel(
    const float* __restrict__ x,
    const float* __restrict__ logits, const float* __restrict__ g,
    const float* __restrict__ w0, const float* __restrict__ w1,
    const float* __restrict__ w2, const float* __restrict__ w3,
    const float* __restrict__ w4,
    const float* __restrict__ gamma, const float* __restrict__ beta,
    const float* __restrict__ mean, const float* __restrict__ var,
    float* __restrict__ out) {
    __shared__ float4 tile[NTILE];

    int t   = threadIdx.x;
    int blk = blockIdx.x;
    int bw  = blk & 7;             // WW/TW = 8
    int bh  = (blk >> 3) & 31;     // HH/TH = 32
    int b   = blk >> 8;            // batch
    int w0p = bw * TW;
    int h0  = bh * TH;

    // wave-uniform routing: argmax(logits + g), first-max wins
    int idx = 0;
    float best = logits[0] + g[0];
#pragma unroll
    for (int i = 1; i < 5; ++i) {
        float v = logits[i] + g[i];
        if (v > best) { best = v; idx = i; }
    }

    int tx = t & 63;               // lane-consecutive w -> coalesced I/O
    int ty = t >> 6;

    f2 accl[RB] = {f2{0.f,0.f}, f2{0.f,0.f}, f2{0.f,0.f}, f2{0.f,0.f}};
    f2 acch[RB] = {f2{0.f,0.f}, f2{0.f,0.f}, f2{0.f,0.f}, f2{0.f,0.f}};

    if (idx == 0) {
        // 1x1 conv: no reuse -> read global directly (coalesced), skip LDS
        f2 a0 = {w0[0],  w0[1]},  b0 = {w0[2],  w0[3]};
        f2 a1 = {w0[4],  w0[5]},  b1 = {w0[6],  w0[7]};
        f2 a2 = {w0[8],  w0[9]},  b2 = {w0[10], w0[11]};
        f2 a3 = {w0[12], w0[13]}, b3 = {w0[14], w0[15]};
#pragma unroll
        for (int r = 0; r < RB; ++r) {
            float4 p = ldx4(x, b, h0 + ty * RB + r, w0p + tx);
            accl[r] = p.x * a0 + p.y * a1 + p.z * a2 + p.w * a3;
            acch[r] = p.x * b0 + p.y * b1 + p.z * b2 + p.w * b3;
        }
    } else {
        // stage 68x20 input tile (zero-filled SAME halo), coalesced
        for (int k = t; k < NTILE; k += 256) {
            int tr = k / TIW;                  // const-div -> magic mul
            int tc = k - tr * TIW;
            int gr = h0 - 2 + tr;
            int gc = w0p - 2 + tc;
            float4 v = {0.f, 0.f, 0.f, 0.f};
            if (((unsigned)gr < (unsigned)HH) & ((unsigned)gc < (unsigned)WW))
                v = ldx4(x, b, gr, gc);
            tile[k] = v;
        }
        __syncthreads();                       // uniform branch: barrier safe

        switch (idx) {
            case 1: conv_tile<3, false>(tile, w1, tx, ty, accl, acch); break;
            case 2: conv_tile<3, true >(tile, w2, tx, ty, accl, acch); break;
            case 3: conv_tile<5, false>(tile, w3, tx, ty, accl, acch); break;
            case 4: conv_tile<5, true >(tile, w4, tx, ty, accl, acch); break;
        }
    }

    // inference BN + ReLU; routing scale == 1.0 exactly (onehot + soft - soft)
    const float* ga = gamma + idx * 4;
    const float* be = beta + idx * 4;
    const float* mu = mean + idx * 4;
    const float* vr = var + idx * 4;
    f2 ivl = {ga[0] * rsqrtf(vr[0] + EPS), ga[1] * rsqrtf(vr[1] + EPS)};
    f2 ivh = {ga[2] * rsqrtf(vr[2] + EPS), ga[3] * rsqrtf(vr[3] + EPS)};
    f2 shl = f2{be[0], be[1]} - f2{mu[0], mu[1]} * ivl;
    f2 shh = f2{be[2], be[3]} - f2{mu[2], mu[3]} * ivh;

#pragma unroll
    for (int r = 0; r < RB; ++r) {
        f2 ol = accl[r] * ivl + shl;
        f2 oh = acch[r] * ivh + shh;
        float4 o;
        o.x = ol.x > 0.f ? ol.x : 0.f;
        o.y = ol.y > 0.f ? ol.y : 0.f;
        o.z = oh.x > 0.f ? oh.x : 0.f;
        o.w = oh.y > 0.f ? oh.y : 0.f;
        *reinterpret_cast<float4*>(
            out + ((((size_t)b * HH + h0 + ty * RB + r) * WW + w0p + tx) << 2)) = o;
    }
}

extern "C" void kernel_launch(void* const* d_in, const int* in_sizes, int n_in,
                              void* d_out, int out_size, void* d_ws, size_t ws_size,
                              hipStream_t stream) {
    const float* x      = (const float*)d_in[0];
    const float* logits = (const float*)d_in[1];
    const float* g      = (const float*)d_in[2];
    const float* w0     = (const float*)d_in[3];
    const float* w1     = (const float*)d_in[4];
    const float* w2     = (const float*)d_in[5];
    const float* w3     = (const float*)d_in[6];
    const float* w4     = (const float*)d_in[7];
    const float* gamma  = (const float*)d_in[8];
    const float* beta   = (const float*)d_in[9];
    const float* mean   = (const float*)d_in[10];
    const float* var    = (const float*)d_in[11];
    float* out = (float*)d_out;

    const int blocks = NB * (HH / TH) * (WW / TW);  // 8192
    mixop_kernel<<<blocks, 256, 0, stream>>>(
        x, logits, g, w0, w1, w2, w3, w4, gamma, beta, mean, var, out);
}

// Round 5
// 68.631 us; speedup vs baseline: 1.5639x; 1.0929x over previous
//
#include <hip/hip_runtime.h>

typedef float f2 __attribute__((ext_vector_type(2)));

#define HH 512
#define WW 512
#define NB 32
#define TW 64                    // output tile width (px)
#define TH 16                    // output tile height
#define RB 4                     // rows per thread (ty 0..3 -> rows 4ty..4ty+3)
#define TIW (TW + 4)             // 68 (halo P<=2 each side)
#define TIH (TH + 4)             // 20
#define NTILE (TIW * TIH)        // 1360
#define EPS 1e-5f

// Wave-uniform loads routed through the constant address space: backend emits
// s_load (SGPR-resident, SMEM pipe) instead of per-lane global_load + 64-bit
// VGPR address arithmetic. Weights/BN params are uniform and read-only.
__device__ __forceinline__ const __attribute__((address_space(4))) float*
cptr(const float* p) {
    return (const __attribute__((address_space(4))) float*)(unsigned long long)p;
}
__device__ __forceinline__ f2 ldw2(const float* p) {
    const __attribute__((address_space(4))) float* q = cptr(p);
    return f2{q[0], q[1]};
}
__device__ __forceinline__ float ldw1(const float* p) { return cptr(p)[0]; }

__device__ __forceinline__ float4 ldx4(const float* __restrict__ x, int b, int h, int w) {
    return *reinterpret_cast<const float4*>(x + ((((size_t)b * HH + h) * WW + w) << 2));
}

// compute RB vertical output px from the staged tile; weights HWIO (SGPR loads)
template <int K, bool DW>
__device__ __forceinline__ void conv_tile(const float4* __restrict__ tile,  // [TIH][TIW]
                                          const float* __restrict__ wgt,
                                          int tx, int ty,
                                          f2 accl[RB], f2 acch[RB]) {
    constexpr int P = K / 2;
#pragma unroll
    for (int i = 0; i < RB + 2 * P; ++i) {
        const float4* trow = tile + (ty * RB + (2 - P) + i) * TIW + tx + (2 - P);
        float4 win[K];
#pragma unroll
        for (int kj = 0; kj < K; ++kj) win[kj] = trow[kj];
#pragma unroll
        for (int r = 0; r < RB; ++r) {
            int ki = i - r;                       // compile-time per (i,r)
            if (ki < 0 || ki >= K) continue;
#pragma unroll
            for (int kj = 0; kj < K; ++kj) {
                float4 p = win[kj];
                if (DW) {
                    const float* wp = wgt + (ki * K + kj) * 4;   // [c]
                    accl[r] += f2{p.x, p.y} * ldw2(wp + 0);
                    acch[r] += f2{p.z, p.w} * ldw2(wp + 2);
                } else {
                    const float* wp = wgt + (ki * K + kj) * 16;  // [in][out] 4x4
                    accl[r] += p.x * ldw2(wp + 0)  + p.y * ldw2(wp + 4)
                             + p.z * ldw2(wp + 8)  + p.w * ldw2(wp + 12);
                    acch[r] += p.x * ldw2(wp + 2)  + p.y * ldw2(wp + 6)
                             + p.z * ldw2(wp + 10) + p.w * ldw2(wp + 14);
                }
            }
        }
    }
}

__global__ __launch_bounds__(256, 6) void mixop_kernel(
    const float* __restrict__ x,
    const float* __restrict__ logits, const float* __restrict__ g,
    const float* __restrict__ w0, const float* __restrict__ w1,
    const float* __restrict__ w2, const float* __restrict__ w3,
    const float* __restrict__ w4,
    const float* __restrict__ gamma, const float* __restrict__ beta,
    const float* __restrict__ mean, const float* __restrict__ var,
    float* __restrict__ out) {
    __shared__ float4 tile[NTILE];

    int t   = threadIdx.x;
    int blk = blockIdx.x;
    int bw  = blk & 7;             // WW/TW = 8
    int bh  = (blk >> 3) & 31;     // HH/TH = 32
    int b   = blk >> 8;            // batch
    int w0p = bw * TW;
    int h0  = bh * TH;

    // wave-uniform routing: argmax(logits + g), first-max wins (s_load inputs)
    int idx = 0;
    float best = ldw1(logits + 0) + ldw1(g + 0);
#pragma unroll
    for (int i = 1; i < 5; ++i) {
        float v = ldw1(logits + i) + ldw1(g + i);
        if (v > best) { best = v; idx = i; }
    }

    int tx = t & 63;               // lane-consecutive w -> coalesced I/O
    int ty = t >> 6;

    f2 accl[RB] = {f2{0.f,0.f}, f2{0.f,0.f}, f2{0.f,0.f}, f2{0.f,0.f}};
    f2 acch[RB] = {f2{0.f,0.f}, f2{0.f,0.f}, f2{0.f,0.f}, f2{0.f,0.f}};

    if (idx == 0) {
        // 1x1 conv: no reuse -> read global directly (coalesced), skip LDS
        f2 a0 = ldw2(w0 + 0),  b0 = ldw2(w0 + 2);
        f2 a1 = ldw2(w0 + 4),  b1 = ldw2(w0 + 6);
        f2 a2 = ldw2(w0 + 8),  b2 = ldw2(w0 + 10);
        f2 a3 = ldw2(w0 + 12), b3 = ldw2(w0 + 14);
#pragma unroll
        for (int r = 0; r < RB; ++r) {
            float4 p = ldx4(x, b, h0 + ty * RB + r, w0p + tx);
            accl[r] = p.x * a0 + p.y * a1 + p.z * a2 + p.w * a3;
            acch[r] = p.x * b0 + p.y * b1 + p.z * b2 + p.w * b3;
        }
    } else {
        // stage 68x20 input tile (zero-filled SAME halo), coalesced
        for (int k = t; k < NTILE; k += 256) {
            int tr = k / TIW;                  // const-div -> magic mul
            int tc = k - tr * TIW;
            int gr = h0 - 2 + tr;
            int gc = w0p - 2 + tc;
            float4 v = {0.f, 0.f, 0.f, 0.f};
            if (((unsigned)gr < (unsigned)HH) & ((unsigned)gc < (unsigned)WW))
                v = ldx4(x, b, gr, gc);
            tile[k] = v;
        }
        __syncthreads();                       // uniform branch: barrier safe

        switch (idx) {
            case 1: conv_tile<3, false>(tile, w1, tx, ty, accl, acch); break;
            case 2: conv_tile<3, true >(tile, w2, tx, ty, accl, acch); break;
            case 3: conv_tile<5, false>(tile, w3, tx, ty, accl, acch); break;
            case 4: conv_tile<5, true >(tile, w4, tx, ty, accl, acch); break;
        }
    }

    // inference BN + ReLU; routing scale == 1.0 exactly (onehot + soft - soft)
    const float* ga = gamma + idx * 4;
    const float* be = beta + idx * 4;
    const float* mu = mean + idx * 4;
    const float* vr = var + idx * 4;
    f2 g01 = ldw2(ga + 0), g23 = ldw2(ga + 2);
    f2 v01 = ldw2(vr + 0), v23 = ldw2(vr + 2);
    f2 b01 = ldw2(be + 0), b23 = ldw2(be + 2);
    f2 m01 = ldw2(mu + 0), m23 = ldw2(mu + 2);
    f2 ivl = {g01.x * rsqrtf(v01.x + EPS), g01.y * rsqrtf(v01.y + EPS)};
    f2 ivh = {g23.x * rsqrtf(v23.x + EPS), g23.y * rsqrtf(v23.y + EPS)};
    f2 shl = b01 - m01 * ivl;
    f2 shh = b23 - m23 * ivh;

#pragma unroll
    for (int r = 0; r < RB; ++r) {
        f2 ol = accl[r] * ivl + shl;
        f2 oh = acch[r] * ivh + shh;
        float4 o;
        o.x = ol.x > 0.f ? ol.x : 0.f;
        o.y = ol.y > 0.f ? ol.y : 0.f;
        o.z = oh.x > 0.f ? oh.x : 0.f;
        o.w = oh.y > 0.f ? oh.y : 0.f;
        *reinterpret_cast<float4*>(
            out + ((((size_t)b * HH + h0 + ty * RB + r) * WW + w0p + tx) << 2)) = o;
    }
}

extern "C" void kernel_launch(void* const* d_in, const int* in_sizes, int n_in,
                              void* d_out, int out_size, void* d_ws, size_t ws_size,
                              hipStream_t stream) {
    const float* x      = (const float*)d_in[0];
    const float* logits = (const float*)d_in[1];
    const float* g      = (const float*)d_in[2];
    const float* w0     = (const float*)d_in[3];
    const float* w1     = (const float*)d_in[4];
    const float* w2     = (const float*)d_in[5];
    const float* w3     = (const float*)d_in[6];
    const float* w4     = (const float*)d_in[7];
    const float* gamma  = (const float*)d_in[8];
    const float* beta   = (const float*)d_in[9];
    const float* mean   = (const float*)d_in[10];
    const float* var    = (const float*)d_in[11];
    float* out = (float*)d_out;

    const int blocks = NB * (HH / TH) * (WW / TW);  // 8192
    mixop_kernel<<<blocks, 256, 0, stream>>>(
        x, logits, g, w0, w1, w2, w3, w4, gamma, beta, mean, var, out);
}

// Round 6
// 68.548 us; speedup vs baseline: 1.5657x; 1.0012x over previous
//
#include <hip/hip_runtime.h>

typedef float f2 __attribute__((ext_vector_type(2)));

#define HH 512
#define WW 512
#define NB 32
#define TW 64                    // output tile width (px)
#define TH 16                    // output tile height
#define RB 4                     // rows per thread (ty 0..3 -> rows 4ty..4ty+3)
#define NT 8                     // tiles per block (vertical walk)
#define TIW (TW + 4)             // 68 (halo P<=2 each side)
#define TIH (TH + 4)             // 20
#define NTILE (TIW * TIH)        // 1360
#define NSLOT 6                  // ceil(1360/256)
#define EPS 1e-5f

// Wave-uniform loads routed through constant address space -> s_load (SGPR).
__device__ __forceinline__ const __attribute__((address_space(4))) float*
cptr(const float* p) {
    return (const __attribute__((address_space(4))) float*)(unsigned long long)p;
}
__device__ __forceinline__ f2 ldw2(const float* p) {
    const __attribute__((address_space(4))) float* q = cptr(p);
    return f2{q[0], q[1]};
}
__device__ __forceinline__ float ldw1(const float* p) { return cptr(p)[0]; }

__device__ __forceinline__ float4 ldx4(const float* __restrict__ x, int b, int h, int w) {
    return *reinterpret_cast<const float4*>(x + ((((size_t)b * HH + h) * WW + w) << 2));
}

// issue the 6-slot register prefetch for the tile at (b, h0, w0p)
__device__ __forceinline__ void load_pf(const float* __restrict__ x, int b, int h0,
                                        int w0p, const int* tr, const int* tc,
                                        int t, float4 pf[NSLOT]) {
#pragma unroll
    for (int j = 0; j < NSLOT; ++j) {
        if (j == NSLOT - 1 && t >= NTILE - 256 * (NSLOT - 1)) continue;  // slot invalid
        int gr = h0 - 2 + tr[j];
        int gc = w0p - 2 + tc[j];
        float4 v = {0.f, 0.f, 0.f, 0.f};
        if (((unsigned)gr < (unsigned)HH) & ((unsigned)gc < (unsigned)WW))
            v = ldx4(x, b, gr, gc);
        pf[j] = v;
    }
}

// compute RB vertical output px from the staged tile; weights HWIO (SGPR loads)
template <int K, bool DW>
__device__ __forceinline__ void conv_tile(const float4* __restrict__ tile,  // [TIH][TIW]
                                          const float* __restrict__ wgt,
                                          int tx, int ty,
                                          f2 accl[RB], f2 acch[RB]) {
    constexpr int P = K / 2;
#pragma unroll
    for (int i = 0; i < RB + 2 * P; ++i) {
        const float4* trow = tile + (ty * RB + (2 - P) + i) * TIW + tx + (2 - P);
        float4 win[K];
#pragma unroll
        for (int kj = 0; kj < K; ++kj) win[kj] = trow[kj];
#pragma unroll
        for (int r = 0; r < RB; ++r) {
            int ki = i - r;                       // compile-time per (i,r)
            if (ki < 0 || ki >= K) continue;
#pragma unroll
            for (int kj = 0; kj < K; ++kj) {
                float4 p = win[kj];
                if (DW) {
                    const float* wp = wgt + (ki * K + kj) * 4;   // [c]
                    accl[r] += f2{p.x, p.y} * ldw2(wp + 0);
                    acch[r] += f2{p.z, p.w} * ldw2(wp + 2);
                } else {
                    const float* wp = wgt + (ki * K + kj) * 16;  // [in][out] 4x4
                    accl[r] += p.x * ldw2(wp + 0)  + p.y * ldw2(wp + 4)
                             + p.z * ldw2(wp + 8)  + p.w * ldw2(wp + 12);
                    acch[r] += p.x * ldw2(wp + 2)  + p.y * ldw2(wp + 6)
                             + p.z * ldw2(wp + 10) + p.w * ldw2(wp + 14);
                }
            }
        }
    }
}

struct BN { f2 ivl, ivh, shl, shh; };

__device__ __forceinline__ BN make_bn(const float* gamma, const float* beta,
                                      const float* mean, const float* var, int idx) {
    const float* ga = gamma + idx * 4;
    const float* be = beta + idx * 4;
    const float* mu = mean + idx * 4;
    const float* vr = var + idx * 4;
    f2 g01 = ldw2(ga + 0), g23 = ldw2(ga + 2);
    f2 v01 = ldw2(vr + 0), v23 = ldw2(vr + 2);
    f2 b01 = ldw2(be + 0), b23 = ldw2(be + 2);
    f2 m01 = ldw2(mu + 0), m23 = ldw2(mu + 2);
    BN bn;
    bn.ivl = f2{g01.x * rsqrtf(v01.x + EPS), g01.y * rsqrtf(v01.y + EPS)};
    bn.ivh = f2{g23.x * rsqrtf(v23.x + EPS), g23.y * rsqrtf(v23.y + EPS)};
    bn.shl = b01 - m01 * bn.ivl;
    bn.shh = b23 - m23 * bn.ivh;
    return bn;
}

__device__ __forceinline__ void bn_store(float* __restrict__ out, const BN& bn,
                                         const f2 accl[RB], const f2 acch[RB],
                                         int b, int h0, int ty, int w0p, int tx) {
#pragma unroll
    for (int r = 0; r < RB; ++r) {
        f2 ol = accl[r] * bn.ivl + bn.shl;
        f2 oh = acch[r] * bn.ivh + bn.shh;
        float4 o;
        o.x = ol.x > 0.f ? ol.x : 0.f;
        o.y = ol.y > 0.f ? ol.y : 0.f;
        o.z = oh.x > 0.f ? oh.x : 0.f;
        o.w = oh.y > 0.f ? oh.y : 0.f;
        *reinterpret_cast<float4*>(
            out + ((((size_t)b * HH + h0 + ty * RB + r) * WW + w0p + tx) << 2)) = o;
    }
}

// pipelined multi-tile loop: ds_write(i) -> barrier -> issue loads(i+1) ->
// compute(i) -> barrier.  vmcnt drain lands at next iteration's ds_write,
// i.e. AFTER compute -> HBM hides under the pk-FMA stream.
template <int K, bool DW>
__device__ __forceinline__ void run_tiles(const float* __restrict__ x,
                                          float* __restrict__ out,
                                          const float* __restrict__ wgt,
                                          const BN& bn, float4* tile,
                                          int b, int h0b, int w0p,
                                          const int* tr, const int* tc,
                                          int t, int tx, int ty) {
    float4 pf[NSLOT];
    load_pf(x, b, h0b, w0p, tr, tc, t, pf);
#pragma unroll 1
    for (int i = 0; i < NT; ++i) {
        int h0 = h0b + i * TH;
#pragma unroll
        for (int j = 0; j < NSLOT; ++j) {
            if (j == NSLOT - 1 && t >= NTILE - 256 * (NSLOT - 1)) continue;
            tile[t + 256 * j] = pf[j];
        }
        __syncthreads();
        if (i + 1 < NT) load_pf(x, b, h0 + TH, w0p, tr, tc, t, pf);  // issue early
        f2 accl[RB] = {f2{0.f,0.f}, f2{0.f,0.f}, f2{0.f,0.f}, f2{0.f,0.f}};
        f2 acch[RB] = {f2{0.f,0.f}, f2{0.f,0.f}, f2{0.f,0.f}, f2{0.f,0.f}};
        conv_tile<K, DW>(tile, wgt, tx, ty, accl, acch);
        bn_store(out, bn, accl, acch, b, h0, ty, w0p, tx);
        __syncthreads();
    }
}

__global__ __launch_bounds__(256, 4) void mixop_kernel(
    const float* __restrict__ x,
    const float* __restrict__ logits, const float* __restrict__ g,
    const float* __restrict__ w0, const float* __restrict__ w1,
    const float* __restrict__ w2, const float* __restrict__ w3,
    const float* __restrict__ w4,
    const float* __restrict__ gamma, const float* __restrict__ beta,
    const float* __restrict__ mean, const float* __restrict__ var,
    float* __restrict__ out) {
    __shared__ float4 tile[NTILE];

    int t   = threadIdx.x;
    int blk = blockIdx.x;
    int bw  = blk & 7;             // WW/TW = 8
    int hg  = (blk >> 3) & 3;      // HH/(TH*NT) = 4
    int b   = blk >> 5;            // batch
    int w0p = bw * TW;
    int h0b = hg * (TH * NT);

    // wave-uniform routing: argmax(logits + g), first-max wins (s_load inputs)
    int idx = 0;
    float best = ldw1(logits + 0) + ldw1(g + 0);
#pragma unroll
    for (int i = 1; i < 5; ++i) {
        float v = ldw1(logits + i) + ldw1(g + i);
        if (v > best) { best = v; idx = i; }
    }

    int tx = t & 63;               // lane-consecutive w -> coalesced I/O
    int ty = t >> 6;

    BN bn = make_bn(gamma, beta, mean, var, idx);

    if (idx == 0) {
        // 1x1 conv: no reuse -> direct global reads, no LDS/barriers
        f2 a0 = ldw2(w0 + 0),  c0 = ldw2(w0 + 2);
        f2 a1 = ldw2(w0 + 4),  c1 = ldw2(w0 + 6);
        f2 a2 = ldw2(w0 + 8),  c2 = ldw2(w0 + 10);
        f2 a3 = ldw2(w0 + 12), c3 = ldw2(w0 + 14);
#pragma unroll 1
        for (int i = 0; i < NT; ++i) {
            int h0 = h0b + i * TH;
            f2 accl[RB], acch[RB];
#pragma unroll
            for (int r = 0; r < RB; ++r) {
                float4 p = ldx4(x, b, h0 + ty * RB + r, w0p + tx);
                accl[r] = p.x * a0 + p.y * a1 + p.z * a2 + p.w * a3;
                acch[r] = p.x * c0 + p.y * c1 + p.z * c2 + p.w * c3;
            }
            bn_store(out, bn, accl, acch, b, h0, ty, w0p, tx);
        }
        return;
    }

    // per-thread staging coords, computed once per block
    int tr[NSLOT], tc[NSLOT];
#pragma unroll
    for (int j = 0; j < NSLOT; ++j) {
        int k = t + 256 * j;
        tr[j] = k / TIW;
        tc[j] = k - tr[j] * TIW;
    }

    switch (idx) {
        case 1: run_tiles<3, false>(x, out, w1, bn, tile, b, h0b, w0p, tr, tc, t, tx, ty); break;
        case 2: run_tiles<3, true >(x, out, w2, bn, tile, b, h0b, w0p, tr, tc, t, tx, ty); break;
        case 3: run_tiles<5, false>(x, out, w3, bn, tile, b, h0b, w0p, tr, tc, t, tx, ty); break;
        case 4: run_tiles<5, true >(x, out, w4, bn, tile, b, h0b, w0p, tr, tc, t, tx, ty); break;
    }
}

extern "C" void kernel_launch(void* const* d_in, const int* in_sizes, int n_in,
                              void* d_out, int out_size, void* d_ws, size_t ws_size,
                              hipStream_t stream) {
    const float* x      = (const float*)d_in[0];
    const float* logits = (const float*)d_in[1];
    const float* g      = (const float*)d_in[2];
    const float* w0     = (const float*)d_in[3];
    const float* w1     = (const float*)d_in[4];
    const float* w2     = (const float*)d_in[5];
    const float* w3     = (const float*)d_in[6];
    const float* w4     = (const float*)d_in[7];
    const float* gamma  = (const float*)d_in[8];
    const float* beta   = (const float*)d_in[9];
    const float* mean   = (const float*)d_in[10];
    const float* var    = (const float*)d_in[11];
    float* out = (float*)d_out;

    const int blocks = NB * (WW / TW) * (HH / (TH * NT));  // 32*8*4 = 1024
    mixop_kernel<<<blocks, 256, 0, stream>>>(
        x, logits, g, w0, w1, w2, w3, w4, gamma, beta, mean, var, out);
}